// Round 4
// baseline (348.544 us; speedup 1.0000x reference)
//
#include <hip/hip_runtime.h>
#include <hip/hip_fp16.h>

// Qwen3 attention block: B=2 S=2048 HID=1024 NH=16 NKV=8 HD=128, causal.
// R4: attn rewritten — S^T = K*Q^T so P^T-in-registers feeds PV's 16x16x16
//     B-operand directly (no P LDS round-trip); double-buffered async K/V
//     staging (global_load_lds, XOR swizzle), one barrier/iter; 256-thr
//     blocks, q-tile 128, complement-paired grid for perfect balance.

typedef _Float16 f16;
typedef __attribute__((ext_vector_type(8))) _Float16 f16x8;
typedef __attribute__((ext_vector_type(4))) _Float16 f16x4;
typedef __attribute__((ext_vector_type(4))) float f32x4;

__constant__ const float kEps = 1e-6f;
// 1/sqrt(128) * log2(e): Q pre-scaled so attn softmax runs in exp2 domain
__constant__ const float kScaleL2 = 0.1275179120685481f;

// async global->LDS, 16B/lane; lds ptr must be wave-uniform (HW adds lane*16)
#define ASYNC_LD16(gp, lp)                                              \
  __builtin_amdgcn_global_load_lds(                                     \
      (const __attribute__((address_space(1))) void*)(gp),              \
      (__attribute__((address_space(3))) void*)(uint32_t)(uintptr_t)(lp), 16, 0, 0)

// ---------------------------------------------------------------- cast f32->f16
__global__ __launch_bounds__(256) void cast_f32_f16(const float* __restrict__ in,
                                                    f16* __restrict__ out, int n) {
  int i = (blockIdx.x * 256 + threadIdx.x) * 4;
  if (i >= n) return;
  f32x4 v = *reinterpret_cast<const f32x4*>(in + i);
  f16x4 o;
  o.x = (f16)v.x; o.y = (f16)v.y; o.z = (f16)v.z; o.w = (f16)v.w;
  *reinterpret_cast<f16x4*>(out + i) = o;
}

// ------------------------------------------------- C[M,N] = A[M,K] * B[N,K]^T
// 128x128 tile, BK=64, XOR-swizzled LDS, async staging (unchanged from R3).
__global__ __launch_bounds__(256) void gemm_bt(const f16* __restrict__ A,
                                               const f16* __restrict__ Bm,
                                               float* __restrict__ C,
                                               int M, int N, int K) {
  __shared__ __align__(16) f16 As[128][64];
  __shared__ __align__(16) f16 Bs[128][64];
  const int tid = threadIdx.x;
  const int lane = tid & 63;
  const int wave = tid >> 6;
  const int cl = lane & 15;
  const int quad = lane >> 4;
  const int wm = (wave >> 1) * 64;
  const int wn = (wave & 1) * 64;
  const int tm = blockIdx.y * 128;
  const int tn = blockIdx.x * 128;
  const int r0 = tid >> 3;
  const int csw = ((tid & 7) ^ (r0 & 7)) * 8;

  const f16* Ab = A + (size_t)(tm + r0) * K + csw;
  const f16* Bb = Bm + (size_t)(tn + r0) * K + csw;
  char* Al = (char*)As + wave * 1024;
  char* Bl = (char*)Bs + wave * 1024;

  f32x4 acc[4][4] = {};

  for (int k0 = 0; k0 < K; k0 += 64) {
#pragma unroll
    for (int c = 0; c < 4; ++c) {
      ASYNC_LD16(Ab + (size_t)(c * 32) * K + k0, Al + c * 4096);
      ASYNC_LD16(Bb + (size_t)(c * 32) * K + k0, Bl + c * 4096);
    }
    __syncthreads();
#pragma unroll
    for (int kk = 0; kk < 2; ++kk) {
      f16x8 af[4], bf[4];
#pragma unroll
      for (int mi = 0; mi < 4; ++mi)
        af[mi] = *reinterpret_cast<const f16x8*>(
            &As[wm + mi * 16 + cl][((kk * 4 + quad) ^ (cl & 7)) * 8]);
#pragma unroll
      for (int ni = 0; ni < 4; ++ni)
        bf[ni] = *reinterpret_cast<const f16x8*>(
            &Bs[wn + ni * 16 + cl][((kk * 4 + quad) ^ (cl & 7)) * 8]);
#pragma unroll
      for (int mi = 0; mi < 4; ++mi)
#pragma unroll
        for (int ni = 0; ni < 4; ++ni)
          acc[mi][ni] =
              __builtin_amdgcn_mfma_f32_16x16x32_f16(af[mi], bf[ni], acc[mi][ni], 0, 0, 0);
    }
    __syncthreads();
  }
#pragma unroll
  for (int mi = 0; mi < 4; ++mi)
#pragma unroll
    for (int ni = 0; ni < 4; ++ni)
#pragma unroll
      for (int r = 0; r < 4; ++r)
        C[(size_t)(tm + wm + mi * 16 + quad * 4 + r) * N + tn + wn + ni * 16 + cl] =
            acc[mi][ni][r];
}

// -------------------------- RMSNorm + RoPE + transpose for Q,K (wave per row)
// qkvf: (B*S, 4096) fp32 fused [Q 0..2047 | K 2048..3071 | V 3072..4095]
__global__ __launch_bounds__(256) void rope_norm(
    const float* __restrict__ qkvf,
    const float* __restrict__ cosT, const float* __restrict__ sinT,
    const float* __restrict__ qw, const float* __restrict__ kw,
    f16* __restrict__ qt, f16* __restrict__ kt) {
  const int gw = blockIdx.x * 4 + (threadIdx.x >> 6);
  const int lane = threadIdx.x & 63;
  const int head = gw % 24;
  const int bs = gw / 24;
  const bool isq = head < 16;
  const float* src = qkvf + (size_t)bs * 4096 +
                     (isq ? head * 128 : 2048 + (head - 16) * 128);
  const float x1 = src[lane];
  const float x2 = src[lane + 64];
  float ss = x1 * x1 + x2 * x2;
#pragma unroll
  for (int off = 32; off >= 1; off >>= 1) ss += __shfl_xor(ss, off);
  const float rms = rsqrtf(ss * (1.0f / 128.0f) + kEps);
  const float* w = isq ? qw : kw;
  const float n1 = x1 * rms * w[lane];
  const float n2 = x2 * rms * w[lane + 64];
  const float* cb = cosT + (size_t)bs * 128;
  const float* sb = sinT + (size_t)bs * 128;
  const float o1 = n1 * cb[lane] - n2 * sb[lane];
  const float o2 = n2 * cb[lane + 64] + n1 * sb[lane + 64];
  const int b = bs >> 11;
  const int s = bs & 2047;
  f16* dst;
  float sc;
  if (isq) {
    dst = qt + ((size_t)(b * 16 + head) * 2048 + s) * 128;
    sc = kScaleL2;  // 1/sqrt(128) * log2e
  } else {
    dst = kt + ((size_t)(b * 8 + (head - 16)) * 2048 + s) * 128;
    sc = 1.0f;
  }
  dst[lane] = (f16)(o1 * sc);
  dst[lane + 64] = (f16)(o2 * sc);
}

// ------------------------------- V slice of qkvf fp32 -> (B*NKV, HD, S) f16
__global__ __launch_bounds__(256) void v_transpose(const float* __restrict__ qkvf,
                                                   f16* __restrict__ vt) {
  __shared__ f16 tile[64][136];
  const int bh = blockIdx.y;
  const int b = bh >> 3, h = bh & 7;
  const int s0 = blockIdx.x * 64;
  const int tid = threadIdx.x;
#pragma unroll
  for (int i = 0; i < 8; ++i) {
    int c = tid + i * 256;
    int s = c >> 5;
    int d0 = (c & 31) * 4;
    f32x4 v = *reinterpret_cast<const f32x4*>(
        qkvf + (size_t)(b * 2048 + s0 + s) * 4096 + 3072 + h * 128 + d0);
    tile[s][d0 + 0] = (f16)v.x;
    tile[s][d0 + 1] = (f16)v.y;
    tile[s][d0 + 2] = (f16)v.z;
    tile[s][d0 + 3] = (f16)v.w;
  }
  __syncthreads();
#pragma unroll
  for (int i = 0; i < 4; ++i) {
    int c = tid + i * 256;
    int d = c >> 3;
    int sB = (c & 7) * 8;
    f16x8 o;
#pragma unroll
    for (int j = 0; j < 8; ++j) o[j] = tile[sB + j][d];
    *reinterpret_cast<f16x8*>(vt + ((size_t)(b * 8 + h) * 128 + d) * 2048 + s0 + sB) = o;
  }
}

// ------------------------------------------------------- flash attention (causal)
// 512 blocks x 256 threads (4 waves), q-tile 128 (32 q/wave). K-tile 64.
// S^T = K*Q^T -> C-layout holds P^T == PV's B-operand fragment (x16 MFMA):
// no P LDS round-trip. Double-buffered async K/V staging, 1 barrier/iter.
// Grid: group=bid>>5 -> t = group<8 ? 15-group : group-8 (complement pairing
// so concurrent block pairs sum to 34 iters); bh = bid&31 (XCD grouping).
__global__ __launch_bounds__(256) void attn(const f16* __restrict__ Qt,
                                            const f16* __restrict__ Kt,
                                            const f16* __restrict__ Vt,
                                            f16* __restrict__ Ot) {
  __shared__ __align__(16) f16 Kb[2][64 * 128];   // (s,d) XOR-swizzled chunks
  __shared__ __align__(16) f16 Vb[2][128 * 64];   // (d,s) XOR-swizzled chunks

  const int bid = blockIdx.x;
  const int group = bid >> 5;
  const int t = (group < 8) ? (15 - group) : (group - 8);
  const int bh = bid & 31;
  const int q0 = t * 128;
  const int b = bh >> 4, h = bh & 15;
  const int kv = h >> 1;

  const int tid = threadIdx.x;
  const int lane = tid & 63, wv = tid >> 6;
  const int cl = lane & 15, quad = lane >> 4;

  // Q fragments (B-operand of QK^T): B[n=q=cl][k=d=quad*8+j]
  const f16* qbase = Qt + ((size_t)(b * 16 + h) * 2048 + q0 + wv * 32 + cl) * 128;
  f16x8 aq[2][4];
#pragma unroll
  for (int mi = 0; mi < 2; ++mi)
#pragma unroll
    for (int kk = 0; kk < 4; ++kk)
      aq[mi][kk] =
          *reinterpret_cast<const f16x8*>(qbase + mi * 16 * 128 + kk * 32 + quad * 8);

  const f16* kbase = Kt + (size_t)(b * 8 + kv) * 2048 * 128;
  const f16* vbase = Vt + (size_t)(b * 8 + kv) * 128 * 2048;

  // stage one 64x128 K tile + 128x64 V^T tile into buf (8 async calls/wave)
  auto stage = [&](int kt0, int buf) {
#pragma unroll
    for (int cc = 0; cc < 4; ++cc) {
      const int i = (wv * 4 + cc) * 64 + lane;
      const int kr = i >> 4, ksc = i & 15;
      const int kg = (ksc & 8) | ((ksc & 7) ^ (kr & 7));
      ASYNC_LD16(kbase + (size_t)(kt0 + kr) * 128 + kg * 8,
                 (char*)Kb[buf] + (wv * 4 + cc) * 1024);
      const int vr = i >> 3, vsc = i & 7;
      const int vg = vsc ^ (vr & 7);
      ASYNC_LD16(vbase + (size_t)vr * 2048 + kt0 + vg * 8,
                 (char*)Vb[buf] + (wv * 4 + cc) * 1024);
    }
  };

  float m_[2], l_[2];
#pragma unroll
  for (int mi = 0; mi < 2; ++mi) { m_[mi] = -1e30f; l_[mi] = 0.f; }
  f32x4 oacc[8][2] = {};

  const int nIter = (q0 >> 6) + 2;
  stage(0, 0);

#pragma unroll 1
  for (int it = 0; it < nIter; ++it) {
    const int kt0 = it << 6;
    __syncthreads();  // drains vmcnt: tile `it` arrived; buf (it+1)&1 free
    if (it + 1 < nIter) stage(kt0 + 64, (it + 1) & 1);
    const f16* Kc = Kb[it & 1];
    const f16* Vc = Vb[it & 1];

    // ---- S^T = K*Q^T: A=K-frag, B=Q-frag; sacc[ni][mi]: (s=quad*4+r, q=cl)
    f32x4 sacc[4][2] = {};
#pragma unroll
    for (int kk = 0; kk < 4; ++kk)
#pragma unroll
      for (int ni = 0; ni < 4; ++ni) {
        const int sc = ((kk * 4 + quad) & 8) | (((kk * 4 + quad) & 7) ^ (cl & 7));
        f16x8 ak = *reinterpret_cast<const f16x8*>(Kc + (ni * 16 + cl) * 128 + sc * 8);
#pragma unroll
        for (int mi = 0; mi < 2; ++mi)
          sacc[ni][mi] =
              __builtin_amdgcn_mfma_f32_16x16x32_f16(ak, aq[mi][kk], sacc[ni][mi], 0, 0, 0);
      }
    // ---- causal mask (only near-diagonal tiles trigger)
    if (kt0 + 64 > q0 + wv * 32) {
#pragma unroll
      for (int ni = 0; ni < 4; ++ni)
#pragma unroll
        for (int mi = 0; mi < 2; ++mi) {
          const int qg = q0 + wv * 32 + mi * 16 + cl;
#pragma unroll
          for (int r = 0; r < 4; ++r)
            if (kt0 + ni * 16 + quad * 4 + r > qg) sacc[ni][mi][r] = -1e30f;
        }
    }
    // ---- online softmax (exp2 domain); everything indexed at q=cl
    float al[2];
#pragma unroll
    for (int mi = 0; mi < 2; ++mi) {
      float m0 = -1e30f;
#pragma unroll
      for (int ni = 0; ni < 4; ++ni)
#pragma unroll
        for (int r = 0; r < 4; ++r) m0 = fmaxf(m0, sacc[ni][mi][r]);
      m0 = fmaxf(m0, __shfl_xor(m0, 16));
      m0 = fmaxf(m0, __shfl_xor(m0, 32));
      const float nm = fmaxf(m_[mi], m0);
      al[mi] = __builtin_amdgcn_exp2f(m_[mi] - nm);
      m_[mi] = nm;
      float ps = 0.f;
#pragma unroll
      for (int ni = 0; ni < 4; ++ni)
#pragma unroll
        for (int r = 0; r < 4; ++r) {
          const float p = __builtin_amdgcn_exp2f(sacc[ni][mi][r] - nm);
          sacc[ni][mi][r] = p;
          ps += p;
        }
      l_[mi] = l_[mi] * al[mi] + ps;  // lane-partial over this quad's s
    }
    // ---- P^T already in B-operand layout for 16x16x16: cvt to f16
    f16x4 pf[2][4];
#pragma unroll
    for (int mi = 0; mi < 2; ++mi)
#pragma unroll
      for (int ni = 0; ni < 4; ++ni)
#pragma unroll
        for (int r = 0; r < 4; ++r) pf[mi][ni][r] = (f16)sacc[ni][mi][r];
#pragma unroll
    for (int dblk = 0; dblk < 8; ++dblk)
#pragma unroll
      for (int mi = 0; mi < 2; ++mi) oacc[dblk][mi] *= al[mi];
    // ---- PV: D[m=d][n=q] = V^T * P^T; A=V-frag (b64 LDS), B=pf registers
#pragma unroll
    for (int s16 = 0; s16 < 4; ++s16)
#pragma unroll
      for (int dblk = 0; dblk < 8; ++dblk) {
        const int vsc = ((s16 * 2 + (quad >> 1)) ^ (cl & 7));
        f16x4 av = *reinterpret_cast<const f16x4*>(
            Vc + (dblk * 16 + cl) * 64 + vsc * 8 + (quad & 1) * 4);
#pragma unroll
        for (int mi = 0; mi < 2; ++mi)
          oacc[dblk][mi] =
              __builtin_amdgcn_mfma_f32_16x16x16f16(av, pf[mi][s16], oacc[dblk][mi], 0, 0, 0);
      }
  }
  // ---- finalize: reduce lane-partial l across quads, write O (b64 packed)
#pragma unroll
  for (int mi = 0; mi < 2; ++mi) {
    l_[mi] += __shfl_xor(l_[mi], 16);
    l_[mi] += __shfl_xor(l_[mi], 32);
    const float inv = 1.0f / l_[mi];
    const size_t qrow = (size_t)b * 2048 + q0 + wv * 32 + mi * 16 + cl;
#pragma unroll
    for (int dblk = 0; dblk < 8; ++dblk) {
      f16x4 o;
#pragma unroll
      for (int r = 0; r < 4; ++r) o[r] = (f16)(oacc[dblk][mi][r] * inv);
      *reinterpret_cast<f16x4*>(Ot + qrow * 2048 + h * 128 + dblk * 16 + quad * 4) = o;
    }
  }
}

// ---------------------------------------------------------------------- launch
extern "C" void kernel_launch(void* const* d_in, const int* in_sizes, int n_in,
                              void* d_out, int out_size, void* d_ws, size_t ws_size,
                              hipStream_t stream) {
  (void)in_sizes; (void)n_in; (void)out_size; (void)ws_size;
  const float* hidden = (const float*)d_in[0];
  const float* cosT = (const float*)d_in[1];
  const float* sinT = (const float*)d_in[2];
  // d_in[3] = attention_mask: exactly causal triu * -1e9 -> computed analytically
  const float* Wq = (const float*)d_in[4];
  const float* Wk = (const float*)d_in[5];
  const float* Wv = (const float*)d_in[6];
  const float* Wo = (const float*)d_in[7];
  const float* qnw = (const float*)d_in[8];
  const float* knw = (const float*)d_in[9];
  float* out = (float*)d_out;

  char* ws = (char*)d_ws;
  size_t off = 0;
  auto alloc = [&](size_t bytes) {
    char* p = ws + off;
    off += (bytes + 255) & ~(size_t)255;
    return p;
  };
  f16* hb = (f16*)alloc(4096ull * 1024 * 2);
  f16* wqkv = (f16*)alloc(4096ull * 1024 * 2);   // [Wq;Wk;Wv] rows
  f16* wob = (f16*)alloc(1024ull * 2048 * 2);
  float* qkvf = (float*)alloc(4096ull * 4096 * 4);
  f16* qt = (f16*)alloc(32ull * 2048 * 128 * 2);
  f16* kt = (f16*)alloc(16ull * 2048 * 128 * 2);
  f16* vt = (f16*)alloc(16ull * 2048 * 128 * 2);
  f16* ot = (f16*)alloc(4096ull * 2048 * 2);

  cast_f32_f16<<<4096, 256, 0, stream>>>(hidden, hb, 4194304);
  cast_f32_f16<<<2048, 256, 0, stream>>>(Wq, wqkv, 2097152);
  cast_f32_f16<<<1024, 256, 0, stream>>>(Wk, wqkv + 2048ull * 1024, 1048576);
  cast_f32_f16<<<1024, 256, 0, stream>>>(Wv, wqkv + 3072ull * 1024, 1048576);
  cast_f32_f16<<<2048, 256, 0, stream>>>(Wo, wob, 2097152);

  gemm_bt<<<dim3(32, 32), 256, 0, stream>>>(hb, wqkv, qkvf, 4096, 4096, 1024);

  rope_norm<<<24576, 256, 0, stream>>>(qkvf, cosT, sinT, qnw, knw, qt, kt);
  v_transpose<<<dim3(32, 16), 256, 0, stream>>>(qkvf, vt);

  attn<<<512, 256, 0, stream>>>(qt, kt, vt, ot);

  gemm_bt<<<dim3(8, 32), 256, 0, stream>>>(ot, wob, out, 4096, 1024, 2048);
}

// Round 5
// 316.281 us; speedup vs baseline: 1.1020x; 1.1020x over previous
//
#include <hip/hip_runtime.h>
#include <hip/hip_fp16.h>

// Qwen3 attention block: B=2 S=2048 HID=1024 NH=16 NKV=8 HD=128, causal.
// R5: attn reverted to the measured-good R3 version. Non-attn side:
//     single fused cast launch; QKV GEMM emits f16 (halves intermediate
//     traffic); Wo GEMM uses 64x128 tiles (512 blocks, 2/CU).

typedef _Float16 f16;
typedef __attribute__((ext_vector_type(8))) _Float16 f16x8;
typedef __attribute__((ext_vector_type(4))) _Float16 f16x4;
typedef __attribute__((ext_vector_type(4))) float f32x4;

__constant__ const float kEps = 1e-6f;
// 1/sqrt(128) * log2(e): Q pre-scaled so attn softmax runs in exp2 domain
__constant__ const float kScaleL2 = 0.1275179120685481f;

// async global->LDS, 16B/lane; lds ptr must be wave-uniform (HW adds lane*16)
#define ASYNC_LD16(gp, lp)                                              \
  __builtin_amdgcn_global_load_lds(                                     \
      (const __attribute__((address_space(1))) void*)(gp),              \
      (__attribute__((address_space(3))) void*)(uint32_t)(uintptr_t)(lp), 16, 0, 0)

// max/sum reduce across the 16 lanes of a DPP row (our cl group)
__device__ __forceinline__ float dpp_max16(float v) {
  int x;
  x = __builtin_amdgcn_update_dpp(0, __builtin_bit_cast(int, v), 0xB1, 0xF, 0xF, true);
  v = fmaxf(v, __builtin_bit_cast(float, x));
  x = __builtin_amdgcn_update_dpp(0, __builtin_bit_cast(int, v), 0x4E, 0xF, 0xF, true);
  v = fmaxf(v, __builtin_bit_cast(float, x));
  x = __builtin_amdgcn_update_dpp(0, __builtin_bit_cast(int, v), 0x141, 0xF, 0xF, true);
  v = fmaxf(v, __builtin_bit_cast(float, x));
  x = __builtin_amdgcn_update_dpp(0, __builtin_bit_cast(int, v), 0x140, 0xF, 0xF, true);
  v = fmaxf(v, __builtin_bit_cast(float, x));
  return v;
}
__device__ __forceinline__ float dpp_sum16(float v) {
  int x;
  x = __builtin_amdgcn_update_dpp(0, __builtin_bit_cast(int, v), 0xB1, 0xF, 0xF, true);
  v += __builtin_bit_cast(float, x);
  x = __builtin_amdgcn_update_dpp(0, __builtin_bit_cast(int, v), 0x4E, 0xF, 0xF, true);
  v += __builtin_bit_cast(float, x);
  x = __builtin_amdgcn_update_dpp(0, __builtin_bit_cast(int, v), 0x141, 0xF, 0xF, true);
  v += __builtin_bit_cast(float, x);
  x = __builtin_amdgcn_update_dpp(0, __builtin_bit_cast(int, v), 0x140, 0xF, 0xF, true);
  v += __builtin_bit_cast(float, x);
  return v;
}

// ------------------------------------------------ fused cast f32->f16 (all 5)
// chunks of 4 floats; segment prefix (in chunks):
// hidden 1048576 | Wq +524288 | Wk +262144 | Wv +262144 | Wo +524288
__global__ __launch_bounds__(256) void cast_all(
    const float* __restrict__ h, const float* __restrict__ wq,
    const float* __restrict__ wk, const float* __restrict__ wv,
    const float* __restrict__ wo, f16* __restrict__ hb,
    f16* __restrict__ wqkv, f16* __restrict__ wob) {
  const int idx = blockIdx.x * 256 + threadIdx.x;
  const float* src;
  f16* dst;
  int base;
  if (idx < 1048576) { src = h;  dst = hb;                  base = 0; }
  else if (idx < 1572864) { src = wq; dst = wqkv;               base = 1048576; }
  else if (idx < 1835008) { src = wk; dst = wqkv + 2048 * 1024; base = 1572864; }
  else if (idx < 2097152) { src = wv; dst = wqkv + 3072 * 1024; base = 1835008; }
  else { src = wo; dst = wob; base = 2097152; }
  const int i = (idx - base) * 4;
  f32x4 v = *reinterpret_cast<const f32x4*>(src + i);
  f16x4 o;
  o.x = (f16)v.x; o.y = (f16)v.y; o.z = (f16)v.z; o.w = (f16)v.w;
  *reinterpret_cast<f16x4*>(dst + i) = o;
}

// --------------------------- C[M,N] = A[M,K]*B[N,K]^T, f16 out (QKV proj)
// 128x128 tile, BK=64, XOR-swizzled LDS, async staging.
__global__ __launch_bounds__(256) void gemm_bt_h(const f16* __restrict__ A,
                                                 const f16* __restrict__ Bm,
                                                 f16* __restrict__ C,
                                                 int M, int N, int K) {
  __shared__ __align__(16) f16 As[128][64];
  __shared__ __align__(16) f16 Bs[128][64];
  const int tid = threadIdx.x;
  const int lane = tid & 63;
  const int wave = tid >> 6;
  const int cl = lane & 15;
  const int quad = lane >> 4;
  const int wm = (wave >> 1) * 64;
  const int wn = (wave & 1) * 64;
  const int tm = blockIdx.y * 128;
  const int tn = blockIdx.x * 128;
  const int r0 = tid >> 3;
  const int csw = ((tid & 7) ^ (r0 & 7)) * 8;

  const f16* Ab = A + (size_t)(tm + r0) * K + csw;
  const f16* Bb = Bm + (size_t)(tn + r0) * K + csw;
  char* Al = (char*)As + wave * 1024;
  char* Bl = (char*)Bs + wave * 1024;

  f32x4 acc[4][4] = {};

  for (int k0 = 0; k0 < K; k0 += 64) {
#pragma unroll
    for (int c = 0; c < 4; ++c) {
      ASYNC_LD16(Ab + (size_t)(c * 32) * K + k0, Al + c * 4096);
      ASYNC_LD16(Bb + (size_t)(c * 32) * K + k0, Bl + c * 4096);
    }
    __syncthreads();
#pragma unroll
    for (int kk = 0; kk < 2; ++kk) {
      f16x8 af[4], bf[4];
#pragma unroll
      for (int mi = 0; mi < 4; ++mi)
        af[mi] = *reinterpret_cast<const f16x8*>(
            &As[wm + mi * 16 + cl][((kk * 4 + quad) ^ (cl & 7)) * 8]);
#pragma unroll
      for (int ni = 0; ni < 4; ++ni)
        bf[ni] = *reinterpret_cast<const f16x8*>(
            &Bs[wn + ni * 16 + cl][((kk * 4 + quad) ^ (cl & 7)) * 8]);
#pragma unroll
      for (int mi = 0; mi < 4; ++mi)
#pragma unroll
        for (int ni = 0; ni < 4; ++ni)
          acc[mi][ni] =
              __builtin_amdgcn_mfma_f32_16x16x32_f16(af[mi], bf[ni], acc[mi][ni], 0, 0, 0);
    }
    __syncthreads();
  }
#pragma unroll
  for (int mi = 0; mi < 4; ++mi)
#pragma unroll
    for (int ni = 0; ni < 4; ++ni)
#pragma unroll
      for (int r = 0; r < 4; ++r)
        C[(size_t)(tm + wm + mi * 16 + quad * 4 + r) * N + tn + wn + ni * 16 + cl] =
            (f16)acc[mi][ni][r];
}

// --------------------------- C[M,N] = A[M,K]*B[N,K]^T, f32 out (out proj)
// 64x128 tile (512 blocks for M=4096,N=1024 -> 2 blocks/CU), BK=64.
__global__ __launch_bounds__(256) void gemm_bt64(const f16* __restrict__ A,
                                                 const f16* __restrict__ Bm,
                                                 float* __restrict__ C,
                                                 int M, int N, int K) {
  __shared__ __align__(16) f16 As[64][64];
  __shared__ __align__(16) f16 Bs[128][64];
  const int tid = threadIdx.x;
  const int lane = tid & 63;
  const int wave = tid >> 6;
  const int cl = lane & 15;
  const int quad = lane >> 4;
  const int wm = (wave >> 1) * 32;
  const int wn = (wave & 1) * 64;
  const int tm = blockIdx.y * 64;
  const int tn = blockIdx.x * 128;
  const int r0 = tid >> 3;                     // 0..31 per 256-chunk call
  const int csw = ((tid & 7) ^ (r0 & 7)) * 8;

  const f16* Ab = A + (size_t)(tm + r0) * K + csw;
  const f16* Bb = Bm + (size_t)(tn + r0) * K + csw;
  char* Al = (char*)As + wave * 1024;
  char* Bl = (char*)Bs + wave * 1024;

  f32x4 acc[2][4] = {};

  for (int k0 = 0; k0 < K; k0 += 64) {
#pragma unroll
    for (int c = 0; c < 2; ++c)
      ASYNC_LD16(Ab + (size_t)(c * 32) * K + k0, Al + c * 4096);
#pragma unroll
    for (int c = 0; c < 4; ++c)
      ASYNC_LD16(Bb + (size_t)(c * 32) * K + k0, Bl + c * 4096);
    __syncthreads();
#pragma unroll
    for (int kk = 0; kk < 2; ++kk) {
      f16x8 af[2], bf[4];
#pragma unroll
      for (int mi = 0; mi < 2; ++mi)
        af[mi] = *reinterpret_cast<const f16x8*>(
            &As[wm + mi * 16 + cl][((kk * 4 + quad) ^ (cl & 7)) * 8]);
#pragma unroll
      for (int ni = 0; ni < 4; ++ni)
        bf[ni] = *reinterpret_cast<const f16x8*>(
            &Bs[wn + ni * 16 + cl][((kk * 4 + quad) ^ (cl & 7)) * 8]);
#pragma unroll
      for (int mi = 0; mi < 2; ++mi)
#pragma unroll
        for (int ni = 0; ni < 4; ++ni)
          acc[mi][ni] =
              __builtin_amdgcn_mfma_f32_16x16x32_f16(af[mi], bf[ni], acc[mi][ni], 0, 0, 0);
    }
    __syncthreads();
  }
#pragma unroll
  for (int mi = 0; mi < 2; ++mi)
#pragma unroll
    for (int ni = 0; ni < 4; ++ni)
#pragma unroll
      for (int r = 0; r < 4; ++r)
        C[(size_t)(tm + wm + mi * 16 + quad * 4 + r) * N + tn + wn + ni * 16 + cl] =
            acc[mi][ni][r];
}

// -------------------------- RMSNorm + RoPE + transpose for Q,K (wave per row)
// qkvh: (B*S, 4096) f16 fused [Q 0..2047 | K 2048..3071 | V 3072..4095]
__global__ __launch_bounds__(256) void rope_norm(
    const f16* __restrict__ qkvh,
    const float* __restrict__ cosT, const float* __restrict__ sinT,
    const float* __restrict__ qw, const float* __restrict__ kw,
    f16* __restrict__ qt, f16* __restrict__ kt) {
  const int gw = blockIdx.x * 4 + (threadIdx.x >> 6);
  const int lane = threadIdx.x & 63;
  const int head = gw % 24;
  const int bs = gw / 24;
  const bool isq = head < 16;
  const f16* src = qkvh + (size_t)bs * 4096 +
                   (isq ? head * 128 : 2048 + (head - 16) * 128);
  const float x1 = (float)src[lane];
  const float x2 = (float)src[lane + 64];
  float ss = x1 * x1 + x2 * x2;
#pragma unroll
  for (int off = 32; off >= 1; off >>= 1) ss += __shfl_xor(ss, off);
  const float rms = rsqrtf(ss * (1.0f / 128.0f) + kEps);
  const float* w = isq ? qw : kw;
  const float n1 = x1 * rms * w[lane];
  const float n2 = x2 * rms * w[lane + 64];
  const float* cb = cosT + (size_t)bs * 128;
  const float* sb = sinT + (size_t)bs * 128;
  const float o1 = n1 * cb[lane] - n2 * sb[lane];
  const float o2 = n2 * cb[lane + 64] + n1 * sb[lane + 64];
  const int b = bs >> 11;
  const int s = bs & 2047;
  f16* dst;
  float sc;
  if (isq) {
    dst = qt + ((size_t)(b * 16 + head) * 2048 + s) * 128;
    sc = kScaleL2;  // 1/sqrt(128) * log2e
  } else {
    dst = kt + ((size_t)(b * 8 + (head - 16)) * 2048 + s) * 128;
    sc = 1.0f;
  }
  dst[lane] = (f16)(o1 * sc);
  dst[lane + 64] = (f16)(o2 * sc);
}

// ------------------------------- V slice of qkvh f16 -> (B*NKV, HD, S) f16
__global__ __launch_bounds__(256) void v_transpose(const f16* __restrict__ qkvh,
                                                   f16* __restrict__ vt) {
  __shared__ __align__(16) f16 tile[64][136];
  const int bh = blockIdx.y;
  const int b = bh >> 3, h = bh & 7;
  const int s0 = blockIdx.x * 64;
  const int tid = threadIdx.x;
#pragma unroll
  for (int i = 0; i < 4; ++i) {
    int c = tid + i * 256;  // 1024 chunks of 8 f16
    int s = c >> 4;
    int cg = c & 15;
    f16x8 v = *reinterpret_cast<const f16x8*>(
        qkvh + (size_t)(b * 2048 + s0 + s) * 4096 + 3072 + h * 128 + cg * 8);
    *reinterpret_cast<f16x8*>(&tile[s][cg * 8]) = v;
  }
  __syncthreads();
#pragma unroll
  for (int i = 0; i < 4; ++i) {
    int c = tid + i * 256;
    int d = c >> 3;
    int sB = (c & 7) * 8;
    f16x8 o;
#pragma unroll
    for (int j = 0; j < 8; ++j) o[j] = tile[sB + j][d];
    *reinterpret_cast<f16x8*>(vt + ((size_t)(b * 8 + h) * 128 + d) * 2048 + s0 + sB) = o;
  }
}

// ------------------------------------------------------- flash attention (causal)
// (identical to R3's measured-good version)
// 1024 blocks of 128 threads (2 waves), each wave owns 32 q-rows; K-tile 64.
__global__ __launch_bounds__(128) void attn(const f16* __restrict__ Qt,
                                            const f16* __restrict__ Kt,
                                            const f16* __restrict__ Vt,
                                            f16* __restrict__ Ot) {
  __shared__ __align__(16) f16 Ks[64][136];   // stride 272B = 4 banks mod 32
  __shared__ __align__(16) f16 Vs[128][72];   // stride 144B = 4 banks mod 32
  __shared__ __align__(16) f16 Ps[2][32][72]; // per-wave P round-trip

  const int bid = blockIdx.x;
  const int bh = bid & 31;
  const int t = 31 - (bid >> 5);   // longest tiles first
  const int q0 = t * 64;
  const int b = bh >> 4, h = bh & 15;
  const int kv = h >> 1;

  const int tid = threadIdx.x;
  const int lane = tid & 63, wv = tid >> 6;
  const int cl = lane & 15, quad = lane >> 4;

  const f16* qbase = Qt + ((size_t)(b * 16 + h) * 2048 + q0 + wv * 32 + cl) * 128;
  f16x8 aq[2][4];
#pragma unroll
  for (int mi = 0; mi < 2; ++mi)
#pragma unroll
    for (int kk = 0; kk < 4; ++kk)
      aq[mi][kk] =
          *reinterpret_cast<const f16x8*>(qbase + mi * 16 * 128 + kk * 32 + quad * 8);

  const f16* kbase = Kt + (size_t)(b * 8 + kv) * 2048 * 128;
  const f16* vbase = Vt + (size_t)(b * 8 + kv) * 128 * 2048;

  float m_[2][4], l_[2][4];
#pragma unroll
  for (int mi = 0; mi < 2; ++mi)
#pragma unroll
    for (int r = 0; r < 4; ++r) { m_[mi][r] = -1e30f; l_[mi][r] = 0.f; }
  f32x4 oacc[2][8] = {};

  for (int kt0 = 0; kt0 <= q0; kt0 += 64) {
#pragma unroll
    for (int i = 0; i < 8; ++i) {
      int c = tid + i * 128;
      int krow = c >> 4, d0 = (c & 15) * 8;
      *reinterpret_cast<int4*>(&Ks[krow][d0]) =
          *reinterpret_cast<const int4*>(kbase + (size_t)(kt0 + krow) * 128 + d0);
      int dr = c >> 3, ko = (c & 7) * 8;
      *reinterpret_cast<int4*>(&Vs[dr][ko]) =
          *reinterpret_cast<const int4*>(vbase + (size_t)dr * 2048 + kt0 + ko);
    }
    __syncthreads();
    f32x4 sacc[2][4] = {};
#pragma unroll
    for (int kk = 0; kk < 4; ++kk)
#pragma unroll
      for (int ni = 0; ni < 4; ++ni) {
        f16x8 bk = *reinterpret_cast<const f16x8*>(&Ks[ni * 16 + cl][kk * 32 + quad * 8]);
#pragma unroll
        for (int mi = 0; mi < 2; ++mi)
          sacc[mi][ni] =
              __builtin_amdgcn_mfma_f32_16x16x32_f16(aq[mi][kk], bk, sacc[mi][ni], 0, 0, 0);
      }
    if (kt0 == q0) {
#pragma unroll
      for (int mi = 0; mi < 2; ++mi) {
        const int qr = wv * 32 + mi * 16 + quad * 4;
#pragma unroll
        for (int ni = 0; ni < 4; ++ni) {
          const int kg = ni * 16 + cl;
#pragma unroll
          for (int r = 0; r < 4; ++r)
            if (kg > qr + r) sacc[mi][ni][r] = -1e30f;
        }
      }
    }
    float alv[2][4];
#pragma unroll
    for (int mi = 0; mi < 2; ++mi)
#pragma unroll
      for (int r = 0; r < 4; ++r) {
        float mx = fmaxf(fmaxf(sacc[mi][0][r], sacc[mi][1][r]),
                         fmaxf(sacc[mi][2][r], sacc[mi][3][r]));
        mx = dpp_max16(mx);
        const float nm = fmaxf(m_[mi][r], mx);
        const float al = __builtin_amdgcn_exp2f(m_[mi][r] - nm);
        m_[mi][r] = nm;
        float ps = 0.f;
#pragma unroll
        for (int ni = 0; ni < 4; ++ni) {
          const float p = __builtin_amdgcn_exp2f(sacc[mi][ni][r] - nm);
          sacc[mi][ni][r] = p;
          ps += p;
        }
        l_[mi][r] = l_[mi][r] * al + ps;
        alv[mi][r] = al;
      }
#pragma unroll
    for (int mi = 0; mi < 2; ++mi)
#pragma unroll
      for (int ni = 0; ni < 4; ++ni)
#pragma unroll
        for (int r = 0; r < 4; ++r)
          Ps[wv][mi * 16 + quad * 4 + r][ni * 16 + cl] = (f16)sacc[mi][ni][r];
#pragma unroll
    for (int mi = 0; mi < 2; ++mi)
#pragma unroll
      for (int dg = 0; dg < 8; ++dg)
#pragma unroll
        for (int r = 0; r < 4; ++r) oacc[mi][dg][r] *= alv[mi][r];
    asm volatile("s_waitcnt lgkmcnt(0)" ::: "memory");  // Ps is per-wave
    f16x8 ap[2][2];
#pragma unroll
    for (int mi = 0; mi < 2; ++mi)
#pragma unroll
      for (int kh = 0; kh < 2; ++kh)
        ap[mi][kh] =
            *reinterpret_cast<const f16x8*>(&Ps[wv][mi * 16 + cl][kh * 32 + quad * 8]);
#pragma unroll
    for (int kh = 0; kh < 2; ++kh)
#pragma unroll
      for (int dg = 0; dg < 8; ++dg) {
        f16x8 bv = *reinterpret_cast<const f16x8*>(&Vs[dg * 16 + cl][kh * 32 + quad * 8]);
#pragma unroll
        for (int mi = 0; mi < 2; ++mi)
          oacc[mi][dg] =
              __builtin_amdgcn_mfma_f32_16x16x32_f16(ap[mi][kh], bv, oacc[mi][dg], 0, 0, 0);
      }
    __syncthreads();
  }
#pragma unroll
  for (int mi = 0; mi < 2; ++mi)
#pragma unroll
    for (int r = 0; r < 4; ++r) {
      const float inv = 1.0f / dpp_sum16(l_[mi][r]);
      const int qg = q0 + wv * 32 + mi * 16 + quad * 4 + r;
#pragma unroll
      for (int dg = 0; dg < 8; ++dg)
        Ot[(size_t)(b * 2048 + qg) * 2048 + h * 128 + dg * 16 + cl] =
            (f16)(oacc[mi][dg][r] * inv);
    }
}

// ---------------------------------------------------------------------- launch
extern "C" void kernel_launch(void* const* d_in, const int* in_sizes, int n_in,
                              void* d_out, int out_size, void* d_ws, size_t ws_size,
                              hipStream_t stream) {
  (void)in_sizes; (void)n_in; (void)out_size; (void)ws_size;
  const float* hidden = (const float*)d_in[0];
  const float* cosT = (const float*)d_in[1];
  const float* sinT = (const float*)d_in[2];
  // d_in[3] = attention_mask: exactly causal triu * -1e9 -> computed analytically
  const float* Wq = (const float*)d_in[4];
  const float* Wk = (const float*)d_in[5];
  const float* Wv = (const float*)d_in[6];
  const float* Wo = (const float*)d_in[7];
  const float* qnw = (const float*)d_in[8];
  const float* knw = (const float*)d_in[9];
  float* out = (float*)d_out;

  char* ws = (char*)d_ws;
  size_t off = 0;
  auto alloc = [&](size_t bytes) {
    char* p = ws + off;
    off += (bytes + 255) & ~(size_t)255;
    return p;
  };
  f16* hb = (f16*)alloc(4096ull * 1024 * 2);
  f16* wqkv = (f16*)alloc(4096ull * 1024 * 2);   // [Wq;Wk;Wv] rows
  f16* wob = (f16*)alloc(1024ull * 2048 * 2);
  f16* qkvh = (f16*)alloc(4096ull * 4096 * 2);
  f16* qt = (f16*)alloc(32ull * 2048 * 128 * 2);
  f16* kt = (f16*)alloc(16ull * 2048 * 128 * 2);
  f16* vt = (f16*)alloc(16ull * 2048 * 128 * 2);
  f16* ot = (f16*)alloc(4096ull * 2048 * 2);

  cast_all<<<10240, 256, 0, stream>>>(hidden, Wq, Wk, Wv, Wo, hb, wqkv, wob);

  gemm_bt_h<<<dim3(32, 32), 256, 0, stream>>>(hb, wqkv, qkvh, 4096, 4096, 1024);

  rope_norm<<<24576, 256, 0, stream>>>(qkvh, cosT, sinT, qnw, knw, qt, kt);
  v_transpose<<<dim3(32, 16), 256, 0, stream>>>(qkvh, vt);

  attn<<<1024, 128, 0, stream>>>(qt, kt, vt, ot);

  gemm_bt64<<<dim3(8, 64), 256, 0, stream>>>(ot, wob, out, 4096, 1024, 2048);
}